// Round 4
// baseline (366.920 us; speedup 1.0000x reference)
//
#include <hip/hip_runtime.h>
#include <math.h>

#define Vc 5
#define Cc 32
#define Gc 8
#define Dc 32
#define Hc 192
#define Wc 192
#define HWc (Hc*Wc)
#define NSRC (Vc-1)
#define PXB 8            // pixels per block
#define NBLK (HWc/PXB)   // 4608

// output offsets (floats)
#define OFF_DEPTH  0
#define OFF_CONF   (HWc)
#define OFF_ATTN   (2*HWc)
#define OFF_EST    (OFF_ATTN + Dc*HWc)
#define OFF_SW     (OFF_EST + 3*HWc)
#define OFF_WEIGHT (OFF_SW + HWc)
#define OFF_NVAL   (OFF_WEIGHT + NSRC*HWc)
#define OFF_MIN    (OFF_NVAL + Dc*HWc)
#define OFF_MAX    (OFF_MIN + HWc)

// ws layout (floats):
//   [i*15 .. i*15+14]  per-view: rot(9), trans(3), norv(3)
//   [64..127]   per-block depth-min partials (64 blocks)
//   [128..191]  per-block depth-max partials
//   [256 ...]   transposed src features: (NSRC, HW, C) channels-last

#define WS_SRCT 256

__device__ void inv4(const float* A, float* out) {
    float M[4][8];
    for (int r = 0; r < 4; r++) {
        for (int c = 0; c < 4; c++) { M[r][c] = A[r*4+c]; M[r][c+4] = (r == c) ? 1.f : 0.f; }
    }
    for (int col = 0; col < 4; col++) {
        int piv = col; float best = fabsf(M[col][col]);
        for (int r = col+1; r < 4; r++) { float v = fabsf(M[r][col]); if (v > best) { best = v; piv = r; } }
        if (piv != col) for (int c = 0; c < 8; c++) { float t = M[col][c]; M[col][c] = M[piv][c]; M[piv][c] = t; }
        float inv = 1.f / M[col][col];
        for (int c = 0; c < 8; c++) M[col][c] *= inv;
        for (int r = 0; r < 4; r++) {
            if (r == col) continue;
            float f = M[r][col];
            for (int c = 0; c < 8; c++) M[r][c] -= f * M[col][c];
        }
    }
    for (int r = 0; r < 4; r++) for (int c = 0; c < 4; c++) out[r*4+c] = M[r][c+4];
}

__device__ void inv3(const float* A, float* out) {
    float a=A[0],b=A[1],c=A[2],d=A[3],e=A[4],f=A[5],g=A[6],h=A[7],i=A[8];
    float det = a*(e*i-f*h) - b*(d*i-f*g) + c*(d*h-e*g);
    float id = 1.f/det;
    out[0]=(e*i-f*h)*id; out[1]=(c*h-b*i)*id; out[2]=(b*f-c*e)*id;
    out[3]=(f*g-d*i)*id; out[4]=(a*i-c*g)*id; out[5]=(c*d-a*f)*id;
    out[6]=(d*h-e*g)*id; out[7]=(b*g-a*h)*id; out[8]=(a*e-b*d)*id;
}

__global__ __launch_bounds__(256)
void setup_minmax_kernel(const float* __restrict__ rotation,
                         const float* __restrict__ proj,
                         const float* __restrict__ depth,
                         float* __restrict__ wsf) {
    const int tid = blockIdx.x * 256 + threadIdx.x;
    const int n4 = (Dc*HWc) / 4;
    const float4* d4 = (const float4*)depth;
    float mn = 3.4e38f, mx = -3.4e38f;
    for (int idx = tid; idx < n4; idx += 64*256) {
        float4 v = d4[idx];
        mn = fminf(mn, fminf(fminf(v.x, v.y), fminf(v.z, v.w)));
        mx = fmaxf(mx, fmaxf(fmaxf(v.x, v.y), fmaxf(v.z, v.w)));
    }
    for (int off = 32; off; off >>= 1) {
        mn = fminf(mn, __shfl_xor(mn, off));
        mx = fmaxf(mx, __shfl_xor(mx, off));
    }
    __shared__ float smn[4], smx[4];
    const int w = threadIdx.x >> 6;
    if ((threadIdx.x & 63) == 0) { smn[w] = mn; smx[w] = mx; }
    __syncthreads();
    if (threadIdx.x == 0) {
        for (int k = 1; k < 4; k++) { mn = fminf(mn, smn[k]); mx = fmaxf(mx, smx[k]); }
        wsf[64 + blockIdx.x] = mn;
        wsf[128 + blockIdx.x] = mx;
        if (blockIdx.x == 0) {
            float refE[16], refK[16], refNew[16], invRef[16];
            for (int k = 0; k < 16; k++) { refE[k] = proj[k]; refK[k] = proj[16+k]; }
            for (int k = 0; k < 16; k++) refNew[k] = refE[k];
            for (int r = 0; r < 3; r++) for (int c = 0; c < 4; c++) {
                float s = 0.f;
                for (int k = 0; k < 3; k++) s += refK[r*4+k] * refE[k*4+c];
                refNew[r*4+c] = s;
            }
            inv4(refNew, invRef);
            float invR0[9];
            inv3(rotation, invR0);
            for (int i = 0; i < NSRC; i++) {
                const float* E = proj + (i+1)*32;
                const float* K = proj + (i+1)*32 + 16;
                float sNew[16];
                for (int k = 0; k < 16; k++) sNew[k] = E[k];
                for (int r = 0; r < 3; r++) for (int c = 0; c < 4; c++) {
                    float s = 0.f;
                    for (int k = 0; k < 3; k++) s += K[r*4+k] * E[k*4+c];
                    sNew[r*4+c] = s;
                }
                float P[16];
                for (int r = 0; r < 4; r++) for (int c = 0; c < 4; c++) {
                    float s = 0.f;
                    for (int k = 0; k < 4; k++) s += sNew[r*4+k] * invRef[k*4+c];
                    P[r*4+c] = s;
                }
                float* o = wsf + i*15;
                for (int r = 0; r < 3; r++) for (int c = 0; c < 3; c++) o[r*3+c] = P[r*4+c];
                for (int r = 0; r < 3; r++) o[9+r] = P[r*4+3];
                const float* Ri = rotation + (i+1)*9;
                for (int c = 0; c < 3; c++) {
                    float s = 0.f;
                    for (int k = 0; k < 3; k++) s += Ri[2*3+k] * invR0[k*3+c];
                    o[12+c] = s;
                }
            }
        }
    }
}

// (NSRC, C, HW) -> (NSRC, HW, C): LDS-tiled, 64 px x 32 ch per block.
// Coalesced reads (px fastest per channel), contiguous writes (whole tile's
// output is one 8 KB linear range). Pad 33 keeps both phases conflict-free.
__global__ __launch_bounds__(256)
void transpose_kernel(const float* __restrict__ src, float* __restrict__ dst) {
    __shared__ float lds[64*33];
    const int t = threadIdx.x;
    const int v = blockIdx.x / (HWc/64);
    const int j = blockIdx.x % (HWc/64);
    const int hw0 = j*64;
    const float* s = src + (size_t)v*Cc*HWc;
    float* o = dst + (size_t)v*HWc*Cc + (size_t)hw0*Cc;
#pragma unroll
    for (int r = 0; r < 8; r++) {
        int idx = t + r*256;
        int c = idx >> 6, p = idx & 63;
        lds[p*33+c] = s[c*HWc + hw0 + p];
    }
    __syncthreads();
#pragma unroll
    for (int r = 0; r < 8; r++) {
        int idx = t + r*256;
        int p = idx >> 5, c = idx & 31;
        o[idx] = lds[p*33+c];
    }
}

// One lane per (px,d): block = 8 adjacent pixels x 32 depths = 256 threads.
// Gathers hit the channels-last copy: per tap, 8 float4 loads off one base
// (imm offsets) instead of 32 scalar plane-strided loads (R3's latency trap).
__global__ __launch_bounds__(256)
void main_kernel(const float* __restrict__ ref_feature,
                 const float* __restrict__ normal_plane,
                 const float* __restrict__ depth_hypo,
                 const float* __restrict__ w_reg,
                 const float* __restrict__ w_norm,
                 const float* __restrict__ wsf,
                 float* __restrict__ out) {
    const int t = threadIdx.x;
    const int px = t & 7;
    const int d  = t >> 3;     // 0..31
    const int wv = t >> 6;     // wave 0..3
    const int bpix = blockIdx.x * PXB;
    const int by = bpix / Wc;
    const int bx = bpix - by * Wc;
    const int pix = bpix + px;
    const float fxp = (float)(bx + px);
    const float fyp = (float)by;
    const bool dlo0 = ((t & 63) == px);   // d-low bits zero within wave

    __shared__ float bufM[2][32], bufA[2][32], bufB[2][32];

    float refv[Cc];
#pragma unroll
    for (int c = 0; c < Cc; c++) refv[c] = ref_feature[c*HWc + pix];
    float wregv[Gc];
#pragma unroll
    for (int gg = 0; gg < Gc; gg++) wregv[gg] = w_reg[gg];

    const float np0 = normal_plane[pix];
    const float np1 = normal_plane[HWc + pix];
    const float np2 = normal_plane[2*HWc + pix];
    const float depth_d = depth_hypo[d*HWc + pix];

    float acc_cor[Gc];
#pragma unroll
    for (int gg = 0; gg < Gc; gg++) acc_cor[gg] = 0.f;
    float cws_acc = 1e-8f, sumw_acc = 1e-8f, nval_acc = 0.f;

    for (int i = 0; i < NSRC; i++) {
        const int par = i & 1;
        const float* Mv = wsf + i*15;
        const float r00=Mv[0], r01=Mv[1], r02=Mv[2];
        const float r10=Mv[3], r11=Mv[4], r12=Mv[5];
        const float r20=Mv[6], r21=Mv[7], r22=Mv[8];
        const float t0=Mv[9], t1=Mv[10], t2=Mv[11];
        const float nv0=Mv[12], nv1=Mv[13], nv2=Mv[14];

        const float b0 = r00*fxp + r01*fyp + r02;
        const float b1 = r10*fxp + r11*fyp + r12;
        const float b2 = r20*fxp + r21*fyp + r22;

        float z = b2*depth_d + t2;
        if (z == 0.f) z = 1e-9f;
        const float sx = (b0*depth_d + t0) / z;
        const float sy = (b1*depth_d + t1) / z;

        const float fx0 = floorf(sx), fy0 = floorf(sy);
        const float wx = sx - fx0, wy = sy - fy0;
        const float fx1 = fx0 + 1.f, fy1 = fy0 + 1.f;
        const bool ix0 = (fx0 >= 0.f) && (fx0 <= (float)(Wc-1));
        const bool ix1 = (fx1 >= 0.f) && (fx1 <= (float)(Wc-1));
        const bool iy0 = (fy0 >= 0.f) && (fy0 <= (float)(Hc-1));
        const bool iy1 = (fy1 >= 0.f) && (fy1 <= (float)(Hc-1));
        const float w00 = (1.f-wx)*(1.f-wy) * ((ix0 && iy0) ? 1.f : 0.f);
        const float w10 = wx*(1.f-wy)       * ((ix1 && iy0) ? 1.f : 0.f);
        const float w01 = (1.f-wx)*wy       * ((ix0 && iy1) ? 1.f : 0.f);
        const float w11 = wx*wy             * ((ix1 && iy1) ? 1.f : 0.f);
        const int xi0 = (int)fminf(fmaxf(fx0, 0.f), (float)(Wc-1));
        const int xi1 = (int)fminf(fmaxf(fx1, 0.f), (float)(Wc-1));
        const int yi0 = (int)fminf(fmaxf(fy0, 0.f), (float)(Hc-1));
        const int yi1 = (int)fminf(fmaxf(fy1, 0.f), (float)(Hc-1));
        const int b00 = (yi0*Wc + xi0)*Cc, b10 = (yi0*Wc + xi1)*Cc;
        const int b01 = (yi1*Wc + xi0)*Cc, b11 = (yi1*Wc + xi1)*Cc;

        const float* srcT = wsf + WS_SRCT + (size_t)i * HWc * Cc;
        float cf[Gc];
#pragma unroll
        for (int gg = 0; gg < Gc; gg++) cf[gg] = 0.f;
        float valid = 0.f;
#pragma unroll
        for (int q = 0; q < 8; q++) {
            const float4 vA = *(const float4*)(srcT + b00 + q*4);
            const float4 vB = *(const float4*)(srcT + b10 + q*4);
            const float4 vC = *(const float4*)(srcT + b01 + q*4);
            const float4 vD = *(const float4*)(srcT + b11 + q*4);
            const float s0 = w00*vA.x + w10*vB.x + w01*vC.x + w11*vD.x;
            const float s1 = w00*vA.y + w10*vB.y + w01*vC.y + w11*vD.y;
            const float s2 = w00*vA.z + w10*vB.z + w01*vC.z + w11*vD.z;
            const float s3 = w00*vA.w + w10*vB.w + w01*vC.w + w11*vD.w;
            if (q == 0) valid = (s0 != 0.f) ? 1.f : 0.f;
            cf[q>>1] += s0*refv[q*4] + s1*refv[q*4+1] + s2*refv[q*4+2] + s3*refv[q*4+3];
        }
        float s_d = 0.f;
#pragma unroll
        for (int gg = 0; gg < Gc; gg++) s_d += cf[gg];
        s_d *= 0.25f;

        // block-level max over d
        float m = s_d;
        m = fmaxf(m, __shfl_xor(m, 8));
        m = fmaxf(m, __shfl_xor(m, 16));
        m = fmaxf(m, __shfl_xor(m, 32));
        if (dlo0) bufM[par][wv*8 + px] = m;
        __syncthreads();
        m = fmaxf(fmaxf(bufM[par][px],    bufM[par][8+px]),
                  fmaxf(bufM[par][16+px], bufM[par][24+px]));

        const float e = expf(s_d - m);
        const float src_w = fmaxf(np0*nv0 + np1*nv1 + np2*nv2, 0.f) + 0.01f;
        const float sw = src_w * valid;
        float se = e, ss = sw;
        se += __shfl_xor(se, 8);  ss += __shfl_xor(ss, 8);
        se += __shfl_xor(se, 16); ss += __shfl_xor(ss, 16);
        se += __shfl_xor(se, 32); ss += __shfl_xor(ss, 32);
        if (dlo0) { bufA[par][wv*8 + px] = se; bufB[par][wv*8 + px] = ss; }
        __syncthreads();
        se = (bufA[par][px] + bufA[par][8+px]) + (bufA[par][16+px] + bufA[par][24+px]);
        ss = (bufB[par][px] + bufB[par][8+px]) + (bufB[par][16+px] + bufB[par][24+px]);

        const float cor_w = (e / se) * 0.17677669529663687f; // softmax/sqrt(C)
        const float cwsw = cor_w * sw * 0.25f;
#pragma unroll
        for (int gg = 0; gg < Gc; gg++) acc_cor[gg] += cwsw * cf[gg];
        cws_acc  += cor_w;
        sumw_acc += sw;
        nval_acc += valid;
        if (d == 0) out[OFF_WEIGHT + i*HWc + pix] = ss * (1.f/32.f);
    }

    // epilogue
    const float inv_sc = 1.f / (sumw_acc * cws_acc);
    float logit = 0.f;
#pragma unroll
    for (int gg = 0; gg < Gc; gg++) logit += (acc_cor[gg] * inv_sc) * wregv[gg];

    float hmn = wsf[64], hmx = wsf[128];
    for (int k = 1; k < 64; k++) {
        hmn = fminf(hmn, wsf[64+k]);
        hmx = fmaxf(hmx, wsf[128+k]);
    }
    logit += (depth_d - hmn) / (hmx - hmn);

    float m = logit;
    m = fmaxf(m, __shfl_xor(m, 8));
    m = fmaxf(m, __shfl_xor(m, 16));
    m = fmaxf(m, __shfl_xor(m, 32));
    if (dlo0) bufM[0][wv*8 + px] = m;
    __syncthreads();
    m = fmaxf(fmaxf(bufM[0][px],    bufM[0][8+px]),
              fmaxf(bufM[0][16+px], bufM[0][24+px]));
    const float e = expf(logit - m);
    float se = e;
    se += __shfl_xor(se, 8);
    se += __shfl_xor(se, 16);
    se += __shfl_xor(se, 32);
    if (dlo0) bufA[0][wv*8 + px] = se;
    __syncthreads();
    se = (bufA[0][px] + bufA[0][8+px]) + (bufA[0][16+px] + bufA[0][24+px]);
    const float attn = e / se;

    // argmax over d (first max on ties)
    float av = attn; int ai = d;
#pragma unroll
    for (int off = 8; off < 64; off <<= 1) {
        float av2 = __shfl_xor(av, off);
        int   ai2 = __shfl_xor(ai, off);
        if (av2 > av || (av2 == av && ai2 < ai)) { av = av2; ai = ai2; }
    }
    if (dlo0) { bufA[1][wv*8 + px] = av; bufB[1][wv*8 + px] = (float)ai; }
    __syncthreads();
    av = bufA[1][px]; ai = (int)bufB[1][px];
#pragma unroll
    for (int k = 1; k < 4; k++) {
        float av2 = bufA[1][k*8 + px];
        int   ai2 = (int)bufB[1][k*8 + px];
        if (av2 > av || (av2 == av && ai2 < ai)) { av = av2; ai = ai2; }
    }

    out[OFF_ATTN + d*HWc + pix] = attn;
    out[OFF_NVAL + d*HWc + pix] = nval_acc;
    if (d == 0) {
        const float dep_sel = depth_hypo[ai*HWc + pix];
        const float last_itv = depth_hypo[HWc + pix] - depth_hypo[pix];
        out[OFF_DEPTH + pix] = dep_sel;
        out[OFF_CONF + pix]  = av;
        out[OFF_SW + pix]    = sumw_acc * 0.25f;
        out[OFF_MIN + pix]   = dep_sel - last_itv;
        out[OFF_MAX + pix]   = dep_sel + last_itv;
    }
    if (d < 3) {
        float v = np0*w_norm[d*3+0] + np1*w_norm[d*3+1] + np2*w_norm[d*3+2];
        out[OFF_EST + d*HWc + pix] = v;
    }
}

extern "C" void kernel_launch(void* const* d_in, const int* in_sizes, int n_in,
                              void* d_out, int out_size, void* d_ws, size_t ws_size,
                              hipStream_t stream) {
    const float* ref   = (const float*)d_in[0];
    const float* src   = (const float*)d_in[1];
    const float* rot   = (const float*)d_in[2];
    const float* np_   = (const float*)d_in[3];
    const float* proj  = (const float*)d_in[4];
    const float* dh    = (const float*)d_in[5];
    const float* wreg  = (const float*)d_in[6];
    const float* wnorm = (const float*)d_in[7];
    float* out = (float*)d_out;
    float* ws  = (float*)d_ws;

    setup_minmax_kernel<<<64, 256, 0, stream>>>(rot, proj, dh, ws);
    transpose_kernel<<<NSRC*(HWc/64), 256, 0, stream>>>(src, ws + WS_SRCT);
    main_kernel<<<NBLK, 256, 0, stream>>>(ref, np_, dh, wreg, wnorm, ws, out);
}

// Round 7
// 359.318 us; speedup vs baseline: 1.0212x; 1.0212x over previous
//
#include <hip/hip_runtime.h>
#include <math.h>

#define Vc 5
#define Cc 32
#define Gc 8
#define Dc 32
#define Hc 192
#define Wc 192
#define HWc (Hc*Wc)
#define NSRC (Vc-1)
#define PXB 8            // pixels per block
#define NBLK (HWc/PXB)   // 4608 = 8 XCD stripes x 576

// output offsets (floats)
#define OFF_DEPTH  0
#define OFF_CONF   (HWc)
#define OFF_ATTN   (2*HWc)
#define OFF_EST    (OFF_ATTN + Dc*HWc)
#define OFF_SW     (OFF_EST + 3*HWc)
#define OFF_WEIGHT (OFF_SW + HWc)
#define OFF_NVAL   (OFF_WEIGHT + NSRC*HWc)
#define OFF_MIN    (OFF_NVAL + Dc*HWc)
#define OFF_MAX    (OFF_MIN + HWc)

// ws layout (floats):
//   [i*15 .. i*15+14]  per-view: rot(9), trans(3), norv(3)
//   [64..127]   per-block depth-min partials (64 blocks)
//   [128..191]  per-block depth-max partials
//   [256 ...]   transposed src features: (NSRC, HW, C) channels-last

#define WS_SRCT 256

__device__ void inv4(const float* A, float* out) {
    float M[4][8];
    for (int r = 0; r < 4; r++) {
        for (int c = 0; c < 4; c++) { M[r][c] = A[r*4+c]; M[r][c+4] = (r == c) ? 1.f : 0.f; }
    }
    for (int col = 0; col < 4; col++) {
        int piv = col; float best = fabsf(M[col][col]);
        for (int r = col+1; r < 4; r++) { float v = fabsf(M[r][col]); if (v > best) { best = v; piv = r; } }
        if (piv != col) for (int c = 0; c < 8; c++) { float t = M[col][c]; M[col][c] = M[piv][c]; M[piv][c] = t; }
        float inv = 1.f / M[col][col];
        for (int c = 0; c < 8; c++) M[col][c] *= inv;
        for (int r = 0; r < 4; r++) {
            if (r == col) continue;
            float f = M[r][col];
            for (int c = 0; c < 8; c++) M[r][c] -= f * M[col][c];
        }
    }
    for (int r = 0; r < 4; r++) for (int c = 0; c < 4; c++) out[r*4+c] = M[r][c+4];
}

__device__ void inv3(const float* A, float* out) {
    float a=A[0],b=A[1],c=A[2],d=A[3],e=A[4],f=A[5],g=A[6],h=A[7],i=A[8];
    float det = a*(e*i-f*h) - b*(d*i-f*g) + c*(d*h-e*g);
    float id = 1.f/det;
    out[0]=(e*i-f*h)*id; out[1]=(c*h-b*i)*id; out[2]=(b*f-c*e)*id;
    out[3]=(f*g-d*i)*id; out[4]=(a*i-c*g)*id; out[5]=(c*d-a*f)*id;
    out[6]=(d*h-e*g)*id; out[7]=(b*g-a*h)*id; out[8]=(a*e-b*d)*id;
}

__global__ __launch_bounds__(256)
void setup_minmax_kernel(const float* __restrict__ rotation,
                         const float* __restrict__ proj,
                         const float* __restrict__ depth,
                         float* __restrict__ wsf) {
    const int tid = blockIdx.x * 256 + threadIdx.x;
    const int n4 = (Dc*HWc) / 4;
    const float4* d4 = (const float4*)depth;
    float mn = 3.4e38f, mx = -3.4e38f;
    for (int idx = tid; idx < n4; idx += 64*256) {
        float4 v = d4[idx];
        mn = fminf(mn, fminf(fminf(v.x, v.y), fminf(v.z, v.w)));
        mx = fmaxf(mx, fmaxf(fmaxf(v.x, v.y), fmaxf(v.z, v.w)));
    }
    for (int off = 32; off; off >>= 1) {
        mn = fminf(mn, __shfl_xor(mn, off));
        mx = fmaxf(mx, __shfl_xor(mx, off));
    }
    __shared__ float smn[4], smx[4];
    const int w = threadIdx.x >> 6;
    if ((threadIdx.x & 63) == 0) { smn[w] = mn; smx[w] = mx; }
    __syncthreads();
    if (threadIdx.x == 0) {
        for (int k = 1; k < 4; k++) { mn = fminf(mn, smn[k]); mx = fmaxf(mx, smx[k]); }
        wsf[64 + blockIdx.x] = mn;
        wsf[128 + blockIdx.x] = mx;
        if (blockIdx.x == 0) {
            float refE[16], refK[16], refNew[16], invRef[16];
            for (int k = 0; k < 16; k++) { refE[k] = proj[k]; refK[k] = proj[16+k]; }
            for (int k = 0; k < 16; k++) refNew[k] = refE[k];
            for (int r = 0; r < 3; r++) for (int c = 0; c < 4; c++) {
                float s = 0.f;
                for (int k = 0; k < 3; k++) s += refK[r*4+k] * refE[k*4+c];
                refNew[r*4+c] = s;
            }
            inv4(refNew, invRef);
            float invR0[9];
            inv3(rotation, invR0);
            for (int i = 0; i < NSRC; i++) {
                const float* E = proj + (i+1)*32;
                const float* K = proj + (i+1)*32 + 16;
                float sNew[16];
                for (int k = 0; k < 16; k++) sNew[k] = E[k];
                for (int r = 0; r < 3; r++) for (int c = 0; c < 4; c++) {
                    float s = 0.f;
                    for (int k = 0; k < 3; k++) s += K[r*4+k] * E[k*4+c];
                    sNew[r*4+c] = s;
                }
                float P[16];
                for (int r = 0; r < 4; r++) for (int c = 0; c < 4; c++) {
                    float s = 0.f;
                    for (int k = 0; k < 4; k++) s += sNew[r*4+k] * invRef[k*4+c];
                    P[r*4+c] = s;
                }
                float* o = wsf + i*15;
                for (int r = 0; r < 3; r++) for (int c = 0; c < 3; c++) o[r*3+c] = P[r*4+c];
                for (int r = 0; r < 3; r++) o[9+r] = P[r*4+3];
                const float* Ri = rotation + (i+1)*9;
                for (int c = 0; c < 3; c++) {
                    float s = 0.f;
                    for (int k = 0; k < 3; k++) s += Ri[2*3+k] * invR0[k*3+c];
                    o[12+c] = s;
                }
            }
        }
    }
}

// (NSRC, C, HW) -> (NSRC, HW, C): LDS-tiled, 64 px x 32 ch per block.
__global__ __launch_bounds__(256)
void transpose_kernel(const float* __restrict__ src, float* __restrict__ dst) {
    __shared__ float lds[64*33];
    const int t = threadIdx.x;
    const int v = blockIdx.x / (HWc/64);
    const int j = blockIdx.x % (HWc/64);
    const int hw0 = j*64;
    const float* s = src + (size_t)v*Cc*HWc;
    float* o = dst + (size_t)v*HWc*Cc + (size_t)hw0*Cc;
#pragma unroll
    for (int r = 0; r < 8; r++) {
        int idx = t + r*256;
        int c = idx >> 6, p = idx & 63;
        lds[p*33+c] = s[c*HWc + hw0 + p];
    }
    __syncthreads();
#pragma unroll
    for (int r = 0; r < 8; r++) {
        int idx = t + r*256;
        int p = idx >> 5, c = idx & 31;
        o[idx] = lds[p*33+c];
    }
}

// One lane per (px,d): block = 8 adjacent pixels x 32 depths = 256 threads.
// XCD-striped block swizzle: each XCD works a contiguous 24-row band so the
// per-view gather working set (~2.4 MB) fits its 4 MB L2.
// Ref features staged in LDS; hmin/hmax partials reduced by wave 0 via
// shuffles (parallel), NOT a per-thread serial 64-iter scan (the R3/R4
// ~200us epilogue stall theory under test).
__global__ __launch_bounds__(256)
void main_kernel(const float* __restrict__ ref_feature,
                 const float* __restrict__ normal_plane,
                 const float* __restrict__ depth_hypo,
                 const float* __restrict__ w_reg,
                 const float* __restrict__ w_norm,
                 const float* __restrict__ wsf,
                 float* __restrict__ out) {
    const int t = threadIdx.x;
    const int px = t & 7;
    const int d  = t >> 3;     // 0..31
    const int wv = t >> 6;     // wave 0..3
    // XCD-stripe swizzle: consecutive blockIdx round-robin across 8 XCDs;
    // give XCD k the contiguous block range [k*576, (k+1)*576).
    const int bid = (blockIdx.x & 7) * (NBLK/8) + (blockIdx.x >> 3);
    const int bpix = bid * PXB;
    const int by = bpix / Wc;
    const int bx = bpix - by * Wc;
    const int pix = bpix + px;
    const float fxp = (float)(bx + px);
    const float fyp = (float)by;
    const bool dlo0 = ((t & 63) == px);   // d-low bits zero within wave

    __shared__ float bufM[2][32], bufA[2][32], bufB[2][32];
    __shared__ float lds_ref[PXB*36];
    __shared__ float s_hmm[2];

    // stage ref features: lds_ref[px][c], c-major per px, pad 36
    {
        const int c = t >> 3, p = t & 7;
        lds_ref[p*36 + c] = ref_feature[c*HWc + bpix + p];
    }
    // wave 0: parallel reduce of the 64 hmin/hmax partials (2 loads + 6
    // shuffle steps), result broadcast via LDS under the barrier below.
    if (wv == 0) {
        float mn = wsf[64 + t];
        float mx = wsf[128 + t];
        for (int off = 32; off; off >>= 1) {
            mn = fminf(mn, __shfl_xor(mn, off));
            mx = fmaxf(mx, __shfl_xor(mx, off));
        }
        if (t == 0) { s_hmm[0] = mn; s_hmm[1] = mx; }
    }
    float wregv[Gc];
#pragma unroll
    for (int gg = 0; gg < Gc; gg++) wregv[gg] = w_reg[gg];

    const float np0 = normal_plane[pix];
    const float np1 = normal_plane[HWc + pix];
    const float np2 = normal_plane[2*HWc + pix];
    const float depth_d = depth_hypo[d*HWc + pix];

    float acc_cor[Gc];
#pragma unroll
    for (int gg = 0; gg < Gc; gg++) acc_cor[gg] = 0.f;
    float cws_acc = 1e-8f, sumw_acc = 1e-8f, nval_acc = 0.f;
    __syncthreads();   // lds_ref + s_hmm ready

    for (int i = 0; i < NSRC; i++) {
        const int par = i & 1;
        const float* Mv = wsf + i*15;
        const float r00=Mv[0], r01=Mv[1], r02=Mv[2];
        const float r10=Mv[3], r11=Mv[4], r12=Mv[5];
        const float r20=Mv[6], r21=Mv[7], r22=Mv[8];
        const float t0=Mv[9], t1=Mv[10], t2=Mv[11];
        const float nv0=Mv[12], nv1=Mv[13], nv2=Mv[14];

        const float b0 = r00*fxp + r01*fyp + r02;
        const float b1 = r10*fxp + r11*fyp + r12;
        const float b2 = r20*fxp + r21*fyp + r22;

        float z = b2*depth_d + t2;
        if (z == 0.f) z = 1e-9f;
        const float sx = (b0*depth_d + t0) / z;
        const float sy = (b1*depth_d + t1) / z;

        const float fx0 = floorf(sx), fy0 = floorf(sy);
        const float wx = sx - fx0, wy = sy - fy0;
        const float fx1 = fx0 + 1.f, fy1 = fy0 + 1.f;
        const bool ix0 = (fx0 >= 0.f) && (fx0 <= (float)(Wc-1));
        const bool ix1 = (fx1 >= 0.f) && (fx1 <= (float)(Wc-1));
        const bool iy0 = (fy0 >= 0.f) && (fy0 <= (float)(Hc-1));
        const bool iy1 = (fy1 >= 0.f) && (fy1 <= (float)(Hc-1));
        const float w00 = (1.f-wx)*(1.f-wy) * ((ix0 && iy0) ? 1.f : 0.f);
        const float w10 = wx*(1.f-wy)       * ((ix1 && iy0) ? 1.f : 0.f);
        const float w01 = (1.f-wx)*wy       * ((ix0 && iy1) ? 1.f : 0.f);
        const float w11 = wx*wy             * ((ix1 && iy1) ? 1.f : 0.f);
        const int xi0 = (int)fminf(fmaxf(fx0, 0.f), (float)(Wc-1));
        const int xi1 = (int)fminf(fmaxf(fx1, 0.f), (float)(Wc-1));
        const int yi0 = (int)fminf(fmaxf(fy0, 0.f), (float)(Hc-1));
        const int yi1 = (int)fminf(fmaxf(fy1, 0.f), (float)(Hc-1));
        const int b00 = (yi0*Wc + xi0)*Cc, b10 = (yi0*Wc + xi1)*Cc;
        const int b01 = (yi1*Wc + xi0)*Cc, b11 = (yi1*Wc + xi1)*Cc;

        const float* srcT = wsf + WS_SRCT + (size_t)i * HWc * Cc;
        float cf[Gc];
#pragma unroll
        for (int gg = 0; gg < Gc; gg++) cf[gg] = 0.f;
        float valid = 0.f;
#pragma unroll
        for (int q = 0; q < 8; q++) {
            const float4 vA = *(const float4*)(srcT + b00 + q*4);
            const float4 vB = *(const float4*)(srcT + b10 + q*4);
            const float4 vC = *(const float4*)(srcT + b01 + q*4);
            const float4 vD = *(const float4*)(srcT + b11 + q*4);
            const float4 rf = *(const float4*)(lds_ref + px*36 + q*4);
            const float s0 = w00*vA.x + w10*vB.x + w01*vC.x + w11*vD.x;
            const float s1 = w00*vA.y + w10*vB.y + w01*vC.y + w11*vD.y;
            const float s2 = w00*vA.z + w10*vB.z + w01*vC.z + w11*vD.z;
            const float s3 = w00*vA.w + w10*vB.w + w01*vC.w + w11*vD.w;
            if (q == 0) valid = (s0 != 0.f) ? 1.f : 0.f;
            cf[q>>1] += s0*rf.x + s1*rf.y + s2*rf.z + s3*rf.w;
        }
        float s_d = 0.f;
#pragma unroll
        for (int gg = 0; gg < Gc; gg++) s_d += cf[gg];
        s_d *= 0.25f;

        // block-level max over d
        float m = s_d;
        m = fmaxf(m, __shfl_xor(m, 8));
        m = fmaxf(m, __shfl_xor(m, 16));
        m = fmaxf(m, __shfl_xor(m, 32));
        if (dlo0) bufM[par][wv*8 + px] = m;
        __syncthreads();
        m = fmaxf(fmaxf(bufM[par][px],    bufM[par][8+px]),
                  fmaxf(bufM[par][16+px], bufM[par][24+px]));

        const float e = expf(s_d - m);
        const float src_w = fmaxf(np0*nv0 + np1*nv1 + np2*nv2, 0.f) + 0.01f;
        const float sw = src_w * valid;
        float se = e, ss = sw;
        se += __shfl_xor(se, 8);  ss += __shfl_xor(ss, 8);
        se += __shfl_xor(se, 16); ss += __shfl_xor(ss, 16);
        se += __shfl_xor(se, 32); ss += __shfl_xor(ss, 32);
        if (dlo0) { bufA[par][wv*8 + px] = se; bufB[par][wv*8 + px] = ss; }
        __syncthreads();
        se = (bufA[par][px] + bufA[par][8+px]) + (bufA[par][16+px] + bufA[par][24+px]);
        ss = (bufB[par][px] + bufB[par][8+px]) + (bufB[par][16+px] + bufB[par][24+px]);

        const float cor_w = (e / se) * 0.17677669529663687f; // softmax/sqrt(C)
        const float cwsw = cor_w * sw * 0.25f;
#pragma unroll
        for (int gg = 0; gg < Gc; gg++) acc_cor[gg] += cwsw * cf[gg];
        cws_acc  += cor_w;
        sumw_acc += sw;
        nval_acc += valid;
        if (d == 0) out[OFF_WEIGHT + i*HWc + pix] = ss * (1.f/32.f);
    }

    // epilogue
    const float inv_sc = 1.f / (sumw_acc * cws_acc);
    float logit = 0.f;
#pragma unroll
    for (int gg = 0; gg < Gc; gg++) logit += (acc_cor[gg] * inv_sc) * wregv[gg];

    const float hmn = s_hmm[0], hmx = s_hmm[1];
    logit += (depth_d - hmn) / (hmx - hmn);

    float m = logit;
    m = fmaxf(m, __shfl_xor(m, 8));
    m = fmaxf(m, __shfl_xor(m, 16));
    m = fmaxf(m, __shfl_xor(m, 32));
    if (dlo0) bufM[0][wv*8 + px] = m;
    __syncthreads();
    m = fmaxf(fmaxf(bufM[0][px],    bufM[0][8+px]),
              fmaxf(bufM[0][16+px], bufM[0][24+px]));
    const float e = expf(logit - m);
    float se = e;
    se += __shfl_xor(se, 8);
    se += __shfl_xor(se, 16);
    se += __shfl_xor(se, 32);
    if (dlo0) bufA[0][wv*8 + px] = se;
    __syncthreads();
    se = (bufA[0][px] + bufA[0][8+px]) + (bufA[0][16+px] + bufA[0][24+px]);
    const float attn = e / se;

    // argmax over d (first max on ties)
    float av = attn; int ai = d;
#pragma unroll
    for (int off = 8; off < 64; off <<= 1) {
        float av2 = __shfl_xor(av, off);
        int   ai2 = __shfl_xor(ai, off);
        if (av2 > av || (av2 == av && ai2 < ai)) { av = av2; ai = ai2; }
    }
    if (dlo0) { bufA[1][wv*8 + px] = av; bufB[1][wv*8 + px] = (float)ai; }
    __syncthreads();
    av = bufA[1][px]; ai = (int)bufB[1][px];
#pragma unroll
    for (int k = 1; k < 4; k++) {
        float av2 = bufA[1][k*8 + px];
        int   ai2 = (int)bufB[1][k*8 + px];
        if (av2 > av || (av2 == av && ai2 < ai)) { av = av2; ai = ai2; }
    }

    out[OFF_ATTN + d*HWc + pix] = attn;
    out[OFF_NVAL + d*HWc + pix] = nval_acc;
    if (d == 0) {
        const float dep_sel = depth_hypo[ai*HWc + pix];
        const float last_itv = depth_hypo[HWc + pix] - depth_hypo[pix];
        out[OFF_DEPTH + pix] = dep_sel;
        out[OFF_CONF + pix]  = av;
        out[OFF_SW + pix]    = sumw_acc * 0.25f;
        out[OFF_MIN + pix]   = dep_sel - last_itv;
        out[OFF_MAX + pix]   = dep_sel + last_itv;
    }
    // est_normal_plane: rows 0..2, distributed (d, px) -> (row, pixel)
    if (d < 24) {
        const int r = d & 3;
        if (r < 3 && px == (d >> 2)) {
            float v = np0*w_norm[r*3+0] + np1*w_norm[r*3+1] + np2*w_norm[r*3+2];
            out[OFF_EST + r*HWc + pix] = v;
        }
    }
}

extern "C" void kernel_launch(void* const* d_in, const int* in_sizes, int n_in,
                              void* d_out, int out_size, void* d_ws, size_t ws_size,
                              hipStream_t stream) {
    const float* ref   = (const float*)d_in[0];
    const float* src   = (const float*)d_in[1];
    const float* rot   = (const float*)d_in[2];
    const float* np_   = (const float*)d_in[3];
    const float* proj  = (const float*)d_in[4];
    const float* dh    = (const float*)d_in[5];
    const float* wreg  = (const float*)d_in[6];
    const float* wnorm = (const float*)d_in[7];
    float* out = (float*)d_out;
    float* ws  = (float*)d_ws;

    setup_minmax_kernel<<<64, 256, 0, stream>>>(rot, proj, dh, ws);
    transpose_kernel<<<NSRC*(HWc/64), 256, 0, stream>>>(src, ws + WS_SRCT);
    main_kernel<<<NBLK, 256, 0, stream>>>(ref, np_, dh, wreg, wnorm, ws, out);
}

// Round 8
// 295.529 us; speedup vs baseline: 1.2416x; 1.2158x over previous
//
#include <hip/hip_runtime.h>
#include <math.h>

#define Vc 5
#define Cc 32
#define Gc 8
#define Dc 32
#define Hc 192
#define Wc 192
#define HWc (Hc*Wc)
#define NSRC (Vc-1)
#define NBLK (HWc/2)     // 18432 single-wave blocks (2 px x 32 d)

// output offsets (floats)
#define OFF_DEPTH  0
#define OFF_CONF   (HWc)
#define OFF_ATTN   (2*HWc)
#define OFF_EST    (OFF_ATTN + Dc*HWc)
#define OFF_SW     (OFF_EST + 3*HWc)
#define OFF_WEIGHT (OFF_SW + HWc)
#define OFF_NVAL   (OFF_WEIGHT + NSRC*HWc)
#define OFF_MIN    (OFF_NVAL + Dc*HWc)
#define OFF_MAX    (OFF_MIN + HWc)

// ws layout (floats):
//   [i*15 .. i*15+14]  per-view: rot(9), trans(3), norv(3)
//   [64..127]   per-block depth-min partials (64 blocks)
//   [128..191]  per-block depth-max partials
//   [256 ...]   transposed src features: (NSRC, HW, C) channels-last

#define WS_SRCT 256

__device__ void inv4(const float* A, float* out) {
    float M[4][8];
    for (int r = 0; r < 4; r++) {
        for (int c = 0; c < 4; c++) { M[r][c] = A[r*4+c]; M[r][c+4] = (r == c) ? 1.f : 0.f; }
    }
    for (int col = 0; col < 4; col++) {
        int piv = col; float best = fabsf(M[col][col]);
        for (int r = col+1; r < 4; r++) { float v = fabsf(M[r][col]); if (v > best) { best = v; piv = r; } }
        if (piv != col) for (int c = 0; c < 8; c++) { float t = M[col][c]; M[col][c] = M[piv][c]; M[piv][c] = t; }
        float inv = 1.f / M[col][col];
        for (int c = 0; c < 8; c++) M[col][c] *= inv;
        for (int r = 0; r < 4; r++) {
            if (r == col) continue;
            float f = M[r][col];
            for (int c = 0; c < 8; c++) M[r][c] -= f * M[col][c];
        }
    }
    for (int r = 0; r < 4; r++) for (int c = 0; c < 4; c++) out[r*4+c] = M[r][c+4];
}

__device__ void inv3(const float* A, float* out) {
    float a=A[0],b=A[1],c=A[2],d=A[3],e=A[4],f=A[5],g=A[6],h=A[7],i=A[8];
    float det = a*(e*i-f*h) - b*(d*i-f*g) + c*(d*h-e*g);
    float id = 1.f/det;
    out[0]=(e*i-f*h)*id; out[1]=(c*h-b*i)*id; out[2]=(b*f-c*e)*id;
    out[3]=(f*g-d*i)*id; out[4]=(a*i-c*g)*id; out[5]=(c*d-a*f)*id;
    out[6]=(d*h-e*g)*id; out[7]=(b*g-a*h)*id; out[8]=(a*e-b*d)*id;
}

__global__ __launch_bounds__(256)
void setup_minmax_kernel(const float* __restrict__ rotation,
                         const float* __restrict__ proj,
                         const float* __restrict__ depth,
                         float* __restrict__ wsf) {
    const int tid = blockIdx.x * 256 + threadIdx.x;
    const int n4 = (Dc*HWc) / 4;
    const float4* d4 = (const float4*)depth;
    float mn = 3.4e38f, mx = -3.4e38f;
    for (int idx = tid; idx < n4; idx += 64*256) {
        float4 v = d4[idx];
        mn = fminf(mn, fminf(fminf(v.x, v.y), fminf(v.z, v.w)));
        mx = fmaxf(mx, fmaxf(fmaxf(v.x, v.y), fmaxf(v.z, v.w)));
    }
    for (int off = 32; off; off >>= 1) {
        mn = fminf(mn, __shfl_xor(mn, off));
        mx = fmaxf(mx, __shfl_xor(mx, off));
    }
    __shared__ float smn[4], smx[4];
    const int w = threadIdx.x >> 6;
    if ((threadIdx.x & 63) == 0) { smn[w] = mn; smx[w] = mx; }
    __syncthreads();
    if (threadIdx.x == 0) {
        for (int k = 1; k < 4; k++) { mn = fminf(mn, smn[k]); mx = fmaxf(mx, smx[k]); }
        wsf[64 + blockIdx.x] = mn;
        wsf[128 + blockIdx.x] = mx;
        if (blockIdx.x == 0) {
            float refE[16], refK[16], refNew[16], invRef[16];
            for (int k = 0; k < 16; k++) { refE[k] = proj[k]; refK[k] = proj[16+k]; }
            for (int k = 0; k < 16; k++) refNew[k] = refE[k];
            for (int r = 0; r < 3; r++) for (int c = 0; c < 4; c++) {
                float s = 0.f;
                for (int k = 0; k < 3; k++) s += refK[r*4+k] * refE[k*4+c];
                refNew[r*4+c] = s;
            }
            inv4(refNew, invRef);
            float invR0[9];
            inv3(rotation, invR0);
            for (int i = 0; i < NSRC; i++) {
                const float* E = proj + (i+1)*32;
                const float* K = proj + (i+1)*32 + 16;
                float sNew[16];
                for (int k = 0; k < 16; k++) sNew[k] = E[k];
                for (int r = 0; r < 3; r++) for (int c = 0; c < 4; c++) {
                    float s = 0.f;
                    for (int k = 0; k < 3; k++) s += K[r*4+k] * E[k*4+c];
                    sNew[r*4+c] = s;
                }
                float P[16];
                for (int r = 0; r < 4; r++) for (int c = 0; c < 4; c++) {
                    float s = 0.f;
                    for (int k = 0; k < 4; k++) s += sNew[r*4+k] * invRef[k*4+c];
                    P[r*4+c] = s;
                }
                float* o = wsf + i*15;
                for (int r = 0; r < 3; r++) for (int c = 0; c < 3; c++) o[r*3+c] = P[r*4+c];
                for (int r = 0; r < 3; r++) o[9+r] = P[r*4+3];
                const float* Ri = rotation + (i+1)*9;
                for (int c = 0; c < 3; c++) {
                    float s = 0.f;
                    for (int k = 0; k < 3; k++) s += Ri[2*3+k] * invR0[k*3+c];
                    o[12+c] = s;
                }
            }
        }
    }
}

// (NSRC, C, HW) -> (NSRC, HW, C): LDS-tiled, 64 px x 32 ch per block.
__global__ __launch_bounds__(256)
void transpose_kernel(const float* __restrict__ src, float* __restrict__ dst) {
    __shared__ float lds[64*33];
    const int t = threadIdx.x;
    const int v = blockIdx.x / (HWc/64);
    const int j = blockIdx.x % (HWc/64);
    const int hw0 = j*64;
    const float* s = src + (size_t)v*Cc*HWc;
    float* o = dst + (size_t)v*HWc*Cc + (size_t)hw0*Cc;
#pragma unroll
    for (int r = 0; r < 8; r++) {
        int idx = t + r*256;
        int c = idx >> 6, p = idx & 63;
        lds[p*33+c] = s[c*HWc + hw0 + p];
    }
    __syncthreads();
#pragma unroll
    for (int r = 0; r < 8; r++) {
        int idx = t + r*256;
        int p = idx >> 5, c = idx & 31;
        o[idx] = lds[p*33+c];
    }
}

// SINGLE-WAVE blocks: 64 threads = 2 px x 32 d. ZERO __syncthreads, ZERO LDS.
// All d-reductions are 5-step shfl_xor butterflies inside the 32-lane half
// (xor offsets 1..16 never cross the px boundary at bit 5). hmin/hmax: full
// 64-lane butterfly over the per-block partials at block start.
// R7 evidence: 4-wave blocks with 11 block-wide barriers gave 88K-cycle wave
// lifetimes at 30% occupancy with every pipe idle -- barrier/chain-bound.
__global__ __launch_bounds__(64, 4)
void main_kernel(const float* __restrict__ ref_feature,
                 const float* __restrict__ normal_plane,
                 const float* __restrict__ depth_hypo,
                 const float* __restrict__ w_reg,
                 const float* __restrict__ w_norm,
                 const float* __restrict__ wsf,
                 float* __restrict__ out) {
    const int lane = threadIdx.x;   // 0..63
    const int px = lane >> 5;       // 0..1
    const int d  = lane & 31;
    // XCD-stripe swizzle: consecutive blockIdx round-robin across 8 XCDs;
    // give XCD k the contiguous block range [k*2304, (k+1)*2304).
    const int bid = (blockIdx.x & 7) * (NBLK/8) + (blockIdx.x >> 3);
    const int pix = bid*2 + px;
    const int y = pix / Wc;
    const int x = pix - y*Wc;
    const float fxp = (float)x;
    const float fyp = (float)y;

    // global hmin/hmax: full-wave butterfly over the 64 partials
    float hmn = wsf[64 + lane];
    float hmx = wsf[128 + lane];
#pragma unroll
    for (int off = 32; off; off >>= 1) {
        hmn = fminf(hmn, __shfl_xor(hmn, off));
        hmx = fmaxf(hmx, __shfl_xor(hmx, off));
    }

    float refv[Cc];
#pragma unroll
    for (int c = 0; c < Cc; c++) refv[c] = ref_feature[c*HWc + pix];
    float wregv[Gc];
#pragma unroll
    for (int gg = 0; gg < Gc; gg++) wregv[gg] = w_reg[gg];

    const float np0 = normal_plane[pix];
    const float np1 = normal_plane[HWc + pix];
    const float np2 = normal_plane[2*HWc + pix];
    const float depth_d = depth_hypo[d*HWc + pix];

    float acc_cor[Gc];
#pragma unroll
    for (int gg = 0; gg < Gc; gg++) acc_cor[gg] = 0.f;
    float cws_acc = 1e-8f, sumw_acc = 1e-8f, nval_acc = 0.f;

    for (int i = 0; i < NSRC; i++) {
        const float* Mv = wsf + i*15;
        const float r00=Mv[0], r01=Mv[1], r02=Mv[2];
        const float r10=Mv[3], r11=Mv[4], r12=Mv[5];
        const float r20=Mv[6], r21=Mv[7], r22=Mv[8];
        const float t0=Mv[9], t1=Mv[10], t2=Mv[11];
        const float nv0=Mv[12], nv1=Mv[13], nv2=Mv[14];

        const float b0 = r00*fxp + r01*fyp + r02;
        const float b1 = r10*fxp + r11*fyp + r12;
        const float b2 = r20*fxp + r21*fyp + r22;

        float z = b2*depth_d + t2;
        if (z == 0.f) z = 1e-9f;
        const float sx = (b0*depth_d + t0) / z;
        const float sy = (b1*depth_d + t1) / z;

        const float fx0 = floorf(sx), fy0 = floorf(sy);
        const float wx = sx - fx0, wy = sy - fy0;
        const float fx1 = fx0 + 1.f, fy1 = fy0 + 1.f;
        const bool ix0 = (fx0 >= 0.f) && (fx0 <= (float)(Wc-1));
        const bool ix1 = (fx1 >= 0.f) && (fx1 <= (float)(Wc-1));
        const bool iy0 = (fy0 >= 0.f) && (fy0 <= (float)(Hc-1));
        const bool iy1 = (fy1 >= 0.f) && (fy1 <= (float)(Hc-1));
        const float w00 = (1.f-wx)*(1.f-wy) * ((ix0 && iy0) ? 1.f : 0.f);
        const float w10 = wx*(1.f-wy)       * ((ix1 && iy0) ? 1.f : 0.f);
        const float w01 = (1.f-wx)*wy       * ((ix0 && iy1) ? 1.f : 0.f);
        const float w11 = wx*wy             * ((ix1 && iy1) ? 1.f : 0.f);
        const int xi0 = (int)fminf(fmaxf(fx0, 0.f), (float)(Wc-1));
        const int xi1 = (int)fminf(fmaxf(fx1, 0.f), (float)(Wc-1));
        const int yi0 = (int)fminf(fmaxf(fy0, 0.f), (float)(Hc-1));
        const int yi1 = (int)fminf(fmaxf(fy1, 0.f), (float)(Hc-1));
        const int b00 = (yi0*Wc + xi0)*Cc, b10 = (yi0*Wc + xi1)*Cc;
        const int b01 = (yi1*Wc + xi0)*Cc, b11 = (yi1*Wc + xi1)*Cc;

        const float* srcT = wsf + WS_SRCT + (size_t)i * HWc * Cc;
        float cf[Gc];
#pragma unroll
        for (int gg = 0; gg < Gc; gg++) cf[gg] = 0.f;
        float valid = 0.f;
#pragma unroll
        for (int q = 0; q < 8; q++) {
            const float4 vA = *(const float4*)(srcT + b00 + q*4);
            const float4 vB = *(const float4*)(srcT + b10 + q*4);
            const float4 vC = *(const float4*)(srcT + b01 + q*4);
            const float4 vD = *(const float4*)(srcT + b11 + q*4);
            const float s0 = w00*vA.x + w10*vB.x + w01*vC.x + w11*vD.x;
            const float s1 = w00*vA.y + w10*vB.y + w01*vC.y + w11*vD.y;
            const float s2 = w00*vA.z + w10*vB.z + w01*vC.z + w11*vD.z;
            const float s3 = w00*vA.w + w10*vB.w + w01*vC.w + w11*vD.w;
            if (q == 0) valid = (s0 != 0.f) ? 1.f : 0.f;
            cf[q>>1] += s0*refv[q*4] + s1*refv[q*4+1] + s2*refv[q*4+2] + s3*refv[q*4+3];
        }
        float s_d = 0.f;
#pragma unroll
        for (int gg = 0; gg < Gc; gg++) s_d += cf[gg];
        s_d *= 0.25f;

        const float src_w = fmaxf(np0*nv0 + np1*nv1 + np2*nv2, 0.f) + 0.01f;
        const float sw = src_w * valid;

        // d-reductions in-wave: max(s_d), sum(sw) (independent chains)
        float m = s_d, ss = sw;
#pragma unroll
        for (int off = 1; off < 32; off <<= 1) {
            m  = fmaxf(m, __shfl_xor(m, off));
            ss += __shfl_xor(ss, off);
        }
        const float e = expf(s_d - m);
        float se = e;
#pragma unroll
        for (int off = 1; off < 32; off <<= 1) se += __shfl_xor(se, off);

        const float cor_w = (e / se) * 0.17677669529663687f; // softmax/sqrt(C)
        const float cwsw = cor_w * sw * 0.25f;
#pragma unroll
        for (int gg = 0; gg < Gc; gg++) acc_cor[gg] += cwsw * cf[gg];
        cws_acc  += cor_w;
        sumw_acc += sw;
        nval_acc += valid;
        if (d == 0) out[OFF_WEIGHT + i*HWc + pix] = ss * (1.f/32.f);
    }

    // epilogue
    const float inv_sc = 1.f / (sumw_acc * cws_acc);
    float logit = 0.f;
#pragma unroll
    for (int gg = 0; gg < Gc; gg++) logit += (acc_cor[gg] * inv_sc) * wregv[gg];
    logit += (depth_d - hmn) / (hmx - hmn);

    float m = logit;
#pragma unroll
    for (int off = 1; off < 32; off <<= 1) m = fmaxf(m, __shfl_xor(m, off));
    const float e = expf(logit - m);
    float se = e;
#pragma unroll
    for (int off = 1; off < 32; off <<= 1) se += __shfl_xor(se, off);
    const float attn = e / se;

    // argmax over d (first max on ties), in-wave
    float av = attn; int ai = d;
#pragma unroll
    for (int off = 1; off < 32; off <<= 1) {
        float av2 = __shfl_xor(av, off);
        int   ai2 = __shfl_xor(ai, off);
        if (av2 > av || (av2 == av && ai2 < ai)) { av = av2; ai = ai2; }
    }

    out[OFF_ATTN + d*HWc + pix] = attn;
    out[OFF_NVAL + d*HWc + pix] = nval_acc;
    if (d == 0) {
        const float dep_sel = depth_hypo[ai*HWc + pix];
        const float last_itv = depth_hypo[HWc + pix] - depth_hypo[pix];
        out[OFF_DEPTH + pix] = dep_sel;
        out[OFF_CONF + pix]  = av;
        out[OFF_SW + pix]    = sumw_acc * 0.25f;
        out[OFF_MIN + pix]   = dep_sel - last_itv;
        out[OFF_MAX + pix]   = dep_sel + last_itv;
    }
    if (d < 3) {   // all px covered (fixes R7 bug: px 6,7 of old blocks unwritten)
        float v = np0*w_norm[d*3+0] + np1*w_norm[d*3+1] + np2*w_norm[d*3+2];
        out[OFF_EST + d*HWc + pix] = v;
    }
}

extern "C" void kernel_launch(void* const* d_in, const int* in_sizes, int n_in,
                              void* d_out, int out_size, void* d_ws, size_t ws_size,
                              hipStream_t stream) {
    const float* ref   = (const float*)d_in[0];
    const float* src   = (const float*)d_in[1];
    const float* rot   = (const float*)d_in[2];
    const float* np_   = (const float*)d_in[3];
    const float* proj  = (const float*)d_in[4];
    const float* dh    = (const float*)d_in[5];
    const float* wreg  = (const float*)d_in[6];
    const float* wnorm = (const float*)d_in[7];
    float* out = (float*)d_out;
    float* ws  = (float*)d_ws;

    setup_minmax_kernel<<<64, 256, 0, stream>>>(rot, proj, dh, ws);
    transpose_kernel<<<NSRC*(HWc/64), 256, 0, stream>>>(src, ws + WS_SRCT);
    main_kernel<<<NBLK, 64, 0, stream>>>(ref, np_, dh, wreg, wnorm, ws, out);
}